// Round 1
// baseline (239.909 us; speedup 1.0000x reference)
//
#include <hip/hip_runtime.h>

#define LOGZERO -10000000000.0f

// Problem constants (fixed shapes from the reference)
constexpr int Bc    = 8;      // batch
constexpr int Tc    = 500;    // time
constexpr int Oc    = 10000;  // vocab
constexpr int NBH   = 64;     // B * W hyps
constexpr int NHYP  = 8;      // hyps per batch (NBH / Bc)
constexpr int SNUM  = 200;    // scoring ids per hyp
constexpr int BLANK = 0;
constexpr int EOSID = 2;

constexpr int TC     = 4;                  // t-rows per block
constexpr int NCHUNK = (Tc + TC - 1) / TC; // 125
constexpr int NP     = 7;                  // pairs per thread: ceil(1600/256)

__device__ __forceinline__ float logaddexp_f(float a, float b) {
    float m = fmaxf(a, b);
    return m + log1pf(expf(-fabsf(a - b)));
}

// Kernel 1: accumulate sum_t exp(log_phi[t-1,h,k] + x[b,t,ids[h,k]]) into acc[h*SNUM+k]
__global__ __launch_bounds__(256) void ctc_score_kernel(
    const float* __restrict__ x,            // (B, T, O)
    const float* __restrict__ r_prev,       // (T, 2, NBH)
    const int*   __restrict__ xlens,        // (B,)
    const int*   __restrict__ last_ids,     // (NBH,)
    const int*   __restrict__ scoring_ids,  // (NBH, SNUM)
    const int*   __restrict__ olen_p,       // (1,)
    float*       __restrict__ acc_out)      // (NBH, SNUM), pre-zeroed
{
    const int blk = blockIdx.x;
    const int b   = blk / NCHUNK;
    const int c   = blk % NCHUNK;
    const int t0  = c * TC;

    const int ol    = olen_p[0];
    const int start = (ol > 1) ? ol : 1;
    const int tlo   = (ol == 0) ? 0 : start;   // ol==0 contributes the extra t=0 term (r0 = x_[0,0])
    int xlen = xlens[b];
    if (xlen > Tc) xlen = Tc;
    // terms with t >= xlen have x == LOGZERO (except BLANK/EOS cols which are
    // overwritten later) -> exp underflows to exactly 0 -> skip.
    const int lo = (t0 > tlo) ? t0 : tlo;
    const int hi = ((t0 + TC) < xlen) ? (t0 + TC) : xlen;
    if (lo >= hi) return;

    __shared__ __align__(16) float xrow[Oc];
    __shared__ float pno[NHYP];
    __shared__ float phit[NHYP];

    const int tid = threadIdx.x;

    // Per-thread pair setup (pairs p = tid + i*256 over 8 hyps x 200 ids)
    int   sid[NP];
    int   jj[NP];
    bool  hit[NP];
    float acc[NP];
#pragma unroll
    for (int i = 0; i < NP; ++i) {
        acc[i] = 0.0f;
        int p = tid + i * 256;
        if (p < NHYP * SNUM) {
            int j = p / SNUM;
            int k = p - j * SNUM;
            int h = b * NHYP + j;
            int s = scoring_ids[h * SNUM + k];
            sid[i] = s;
            jj[i]  = j;
            hit[i] = (s == last_ids[h]);
        } else {
            sid[i] = 0; jj[i] = 0; hit[i] = false;
        }
    }

    for (int t = lo; t < hi; ++t) {
        // Stage x[b, t, :] into LDS, coalesced float4
        const float4* row4 = (const float4*)(x + (size_t)(b * Tc + t) * Oc);
        float4* x4 = (float4*)xrow;
        for (int idx = tid; idx < Oc / 4; idx += 256) {
            x4[idx] = row4[idx];
        }
        // phi values for t-1 (only needed when t >= 1; t==0 only occurs for ol==0)
        if (tid < NHYP && t > 0) {
            int h = b * NHYP + tid;
            float r0 = r_prev[(size_t)(t - 1) * (2 * NBH) + h];
            float r1 = r_prev[(size_t)(t - 1) * (2 * NBH) + NBH + h];
            phit[tid] = r1;
            pno[tid]  = logaddexp_f(r0, r1);
        }
        __syncthreads();

#pragma unroll
        for (int i = 0; i < NP; ++i) {
            int p = tid + i * 256;
            if (p < NHYP * SNUM) {
                float ph = (t == 0) ? 0.0f : (hit[i] ? phit[jj[i]] : pno[jj[i]]);
                acc[i] += expf(ph + xrow[sid[i]]);
            }
        }
        __syncthreads();
    }

#pragma unroll
    for (int i = 0; i < NP; ++i) {
        int p = tid + i * 256;
        if (p < NHYP * SNUM && acc[i] != 0.0f) {
            int j = jj[i];
            int k = p - j * SNUM;
            int h = b * NHYP + j;
            atomicAdd(&acc_out[h * SNUM + k], acc[i]);
        }
    }
}

// Kernel 2: write full output = val - s_prev; val = LOGZERO everywhere,
// eos_score at EOS, log(acc) at scoring ids (excluding BLANK/EOS).
__global__ __launch_bounds__(256) void ctc_finalize_kernel(
    const float* __restrict__ r_prev,       // (T, 2, NBH)
    const float* __restrict__ s_prev,       // (NBH, O)
    const int*   __restrict__ xlens,        // (B,)
    const int*   __restrict__ scoring_ids,  // (NBH, SNUM)
    const float* __restrict__ acc_in,       // (NBH, SNUM)
    float*       __restrict__ out)          // (NBH, O)
{
    const int h   = blockIdx.x;
    const int b   = h / NHYP;
    const int tid = threadIdx.x;

    const int end = xlens[b] - 1;
    const float r0 = r_prev[(size_t)end * (2 * NBH) + h];
    const float r1 = r_prev[(size_t)end * (2 * NBH) + NBH + h];
    const float eos = logaddexp_f(r0, r1);

    const float4* sp4  = (const float4*)(s_prev + (size_t)h * Oc);
    float4*       out4 = (float4*)(out + (size_t)h * Oc);
    for (int idx = tid; idx < Oc / 4; idx += 256) {
        float4 s = sp4[idx];
        int o = idx * 4;
        float4 v;
        v.x = ((o + 0 == EOSID) ? eos : LOGZERO) - s.x;
        v.y = ((o + 1 == EOSID) ? eos : LOGZERO) - s.y;
        v.z = ((o + 2 == EOSID) ? eos : LOGZERO) - s.z;
        v.w = ((o + 3 == EOSID) ? eos : LOGZERO) - s.w;
        out4[idx] = v;
    }
    __syncthreads();

    if (tid < SNUM) {
        int o = scoring_ids[h * SNUM + tid];
        if (o != BLANK && o != EOSID) {
            float sum = acc_in[h * SNUM + tid];
            sum = fmaxf(sum, 1e-37f);  // guard log(0); unreachable with real data
            float psi = logf(sum);
            out[(size_t)h * Oc + o] = psi - s_prev[(size_t)h * Oc + o];
        }
    }
}

extern "C" void kernel_launch(void* const* d_in, const int* in_sizes, int n_in,
                              void* d_out, int out_size, void* d_ws, size_t ws_size,
                              hipStream_t stream) {
    const float* x           = (const float*)d_in[0];
    const float* r_prev      = (const float*)d_in[1];
    const float* s_prev      = (const float*)d_in[2];
    const int*   xlens       = (const int*)d_in[3];
    const int*   last_ids    = (const int*)d_in[4];
    const int*   scoring_ids = (const int*)d_in[5];
    const int*   olen        = (const int*)d_in[6];
    float* out = (float*)d_out;
    float* acc = (float*)d_ws;  // NBH*SNUM floats = 51.2 KB

    hipMemsetAsync(acc, 0, NBH * SNUM * sizeof(float), stream);
    ctc_score_kernel<<<Bc * NCHUNK, 256, 0, stream>>>(
        x, r_prev, xlens, last_ids, scoring_ids, olen, acc);
    ctc_finalize_kernel<<<NBH, 256, 0, stream>>>(
        r_prev, s_prev, xlens, scoring_ids, acc, out);
}